// Round 1
// baseline (453.487 us; speedup 1.0000x reference)
//
#include <hip/hip_runtime.h>

// Forward kinematics, H36M 32-joint tree, B = 262144.
// R5: occupancy push. R4 was LDS-capped at 5 blocks/CU (31744 B per
// 1-wave block) -> ~1.25 waves/SIMD; kernel ran ~1 TB/s effective while
// the harness fill kernels hit 6.6 TB/s on the same chip => latency-bound,
// not BW-bound.
// Change vs R4: drop the 13312 B lout staging buffer. The two 16-joint
// position halves are packed into VGPRs (float4 ob[12]) and flushed with
// 12 per-lane global_store_dwordx4: 192 B per elem per half = 3 full,
// aligned 64 B sectors, all covered back-to-back inside one store burst,
// so L2 write-combines with no partial-line RMW. This also removes the
// lout ds_write/ds_read round-trip and its lgkm stall from the serial path.
// LDS 31744 -> 18432 B  =>  8 blocks/CU (was 5).
// Input path unchanged (proven): diagonal global_load_lds DMA double
// buffer; vmcnt FIFO accounting identical because the flush still issues
// exactly 12 stores at g==3 and g==7.

#define ASM_VMCNT(N) asm volatile("s_waitcnt vmcnt(" #N ")" ::: "memory")
#define ASM_LGKM0()  asm volatile("s_waitcnt lgkmcnt(0)" ::: "memory")

__global__ __launch_bounds__(64) void fk32_kernel(
    const float* __restrict__ angles,
    const float* __restrict__ offsets,
    float* __restrict__ out,
    int B)
{
    constexpr int PAR[32] = {-1,0,1,2,3,4,0,6,7,8,9,0,11,12,13,14,
                             12,16,17,18,19,20,19,22,12,24,25,26,27,28,27,30};

    const int lane  = threadIdx.x;          // 0..63 (one wave per block)
    const int wbase = blockIdx.x * 64;      // wave's first element

    __shared__ float4 lin[2][576];          // input double buffer, 18432 B (only LDS)

    const float4* __restrict__ gbase =
        reinterpret_cast<const float4*>(angles) + (size_t)wbase * 72u;
    // Per-lane output base: elem (wbase+lane), 24 float4 per elem.
    float4* __restrict__ gout =
        reinterpret_cast<float4*>(out) + (size_t)(wbase + lane) * 24u;

    // Diagonal gather: DMA instr t, lane L fetches tile float4 #n (n=64t+L)
    // at global float4 (n/9)*72 + (n%9); lands at LDS slot n (elem-major).
    const float4* gp[9];
#pragma unroll
    for (int t = 0; t < 9; ++t) {
        const int n = t * 64 + lane;
        const int e = n / 9;
        const int q = n - e * 9;
        gp[t] = gbase + (e * 72 + q);
    }

    // Prologue: group 0 -> buffer 0.
#pragma unroll
    for (int t = 0; t < 9; ++t)
        __builtin_amdgcn_global_load_lds(
            (const __attribute__((address_space(1))) void*)(gp[t]),
            (__attribute__((address_space(3))) void*)(&lin[0][t * 64]),
            16, 0, 0);

    float rot[32][3][3];
    float pos[32][3];
    float4 ob[12];     // 16-joint position half, packed; all indices
                       // compile-time after full unroll -> stays in VGPRs

#pragma unroll
    for (int g = 0; g < 8; ++g) {
        if (g < 7) {
            // Ensure pending ds_reads from the buffer we're about to
            // overwrite have landed in VGPRs.
            ASM_LGKM0();
#pragma unroll
            for (int t = 0; t < 9; ++t)
                __builtin_amdgcn_global_load_lds(
                    (const __attribute__((address_space(1))) void*)(gp[t] + 9 * (g + 1)),
                    (__attribute__((address_space(3))) void*)(&lin[(g + 1) & 1][t * 64]),
                    16, 0, 0);
        }
        // Wait for THIS group's 9 DMAs only (FIFO vmcnt retirement).
        // g==4: FIFO is [g4 x9 | flush0 stores x12 | g5 x9] -> all but the
        //       youngest 21 retired guarantees g4's DMAs are done.
        if (g == 7)      { ASM_VMCNT(0);  }
        else if (g == 4) { ASM_VMCNT(21); }
        else             { ASM_VMCNT(9);  }

        // Own element's 36 floats: 9 x ds_read_b128 (2-way bank alias: free).
        float a[36];
#pragma unroll
        for (int q = 0; q < 9; ++q) {
            const float4 v = lin[g & 1][lane * 9 + q];
            a[4*q+0] = v.x; a[4*q+1] = v.y; a[4*q+2] = v.z; a[4*q+3] = v.w;
        }

#pragma unroll
        for (int jj = 0; jj < 4; ++jj) {
            const int j = g * 4 + jj;
            if (j == 0) {
#pragma unroll
                for (int i = 0; i < 3; ++i)
#pragma unroll
                    for (int l = 0; l < 3; ++l)
                        rot[0][i][l] = a[i*3 + l];
                pos[0][0] = 0.f; pos[0][1] = 0.f; pos[0][2] = 0.f;
            } else {
                const int p = PAR[j];
                const float o0 = offsets[j*3+0];   // uniform -> s_load
                const float o1 = offsets[j*3+1];
                const float o2 = offsets[j*3+2];
#pragma unroll
                for (int l = 0; l < 3; ++l)
                    pos[j][l] = fmaf(o0, rot[p][0][l],
                               fmaf(o1, rot[p][1][l],
                               fmaf(o2, rot[p][2][l], pos[p][l])));
                // rot[j] dead for leaf joints -> DCE.
#pragma unroll
                for (int i = 0; i < 3; ++i) {
                    const float a0 = a[jj*9 + i*3 + 0];
                    const float a1 = a[jj*9 + i*3 + 1];
                    const float a2 = a[jj*9 + i*3 + 2];
#pragma unroll
                    for (int l = 0; l < 3; ++l)
                        rot[j][i][l] = fmaf(a0, rot[p][0][l],
                                      fmaf(a1, rot[p][1][l],
                                           a2 * rot[p][2][l]));
                }
            }
        }

        // Pack this group's 4 joint positions (12 floats = 3 float4) into
        // the register output buffer (indices compile-time under unroll).
        {
            const int gg = g & 3;
            const int j0 = g * 4;
            ob[gg*3 + 0] = make_float4(pos[j0+0][0], pos[j0+0][1], pos[j0+0][2], pos[j0+1][0]);
            ob[gg*3 + 1] = make_float4(pos[j0+1][1], pos[j0+1][2], pos[j0+2][0], pos[j0+2][1]);
            ob[gg*3 + 2] = make_float4(pos[j0+2][2], pos[j0+3][0], pos[j0+3][1], pos[j0+3][2]);
        }

        // Flush pass 0 (joints 0-15) after group 3; pass 1 after group 7.
        // Per-lane contiguous 192 B chunk = 3 full 64 B sectors, written
        // back-to-back -> L2 merges, no partial-line RMW. 12 stores, same
        // vmcnt FIFO footprint as R4's staged flush.
        if (g == 3 || g == 7) {
            const int h = g >> 2;
#pragma unroll
            for (int s = 0; s < 12; ++s)
                gout[h * 12 + s] = ob[s];
        }
    }
}

extern "C" void kernel_launch(void* const* d_in, const int* in_sizes, int n_in,
                              void* d_out, int out_size, void* d_ws, size_t ws_size,
                              hipStream_t stream) {
    const float* angles  = (const float*)d_in[0];
    const float* offsets = (const float*)d_in[1];
    float* out = (float*)d_out;
    const int B = in_sizes[0] / 288;   // [B, 32, 3, 3], B % 64 == 0
    const int block = 64;
    const int grid = B / block;
    fk32_kernel<<<grid, block, 0, stream>>>(angles, offsets, out, B);
}

// Round 2
// 433.957 us; speedup vs baseline: 1.0450x; 1.0450x over previous
//
#include <hip/hip_runtime.h>

// Forward kinematics, H36M 32-joint tree, B = 262144.
// R6 = revert to R4 (proven best). Post-mortem of R5 established:
//   - The bench dur_us includes ~366 us of harness re-poison fills
//     (2 x 183 us fillBufferAligned @ 6.6 TB/s, visible in rocprof).
//   - The kernel itself runs ~67 us in this (R4) form = ~92-95% of the
//     HBM roofline (403 MB minimal traffic / 6.3-6.6 TB/s = 61-64 us).
//   - R5's per-lane register flush (384-B-stride dwordx4 stores,
//     12x the VMEM transactions + re-inflated VGPR pressure) cost +20 us.
// Structure: one wave per block, zero barriers; diagonal global_load_lds
// DMA double-buffer on input; positions staged in padded LDS and flushed
// wave-coalesced in two passes (192 B/elem = 3 aligned full lines).
// LDS 31744 B -> 5 blocks/CU; 9 KB DMA in flight per wave = 45 KB/CU.

#define ASM_VMCNT(N) asm volatile("s_waitcnt vmcnt(" #N ")" ::: "memory")
#define ASM_LGKM0()  asm volatile("s_waitcnt lgkmcnt(0)" ::: "memory")

__global__ __launch_bounds__(64) void fk32_kernel(
    const float* __restrict__ angles,
    const float* __restrict__ offsets,
    float* __restrict__ out,
    int B)
{
    constexpr int PAR[32] = {-1,0,1,2,3,4,0,6,7,8,9,0,11,12,13,14,
                             12,16,17,18,19,20,19,22,12,24,25,26,27,28,27,30};

    const int lane  = threadIdx.x;          // 0..63 (one wave per block)
    const int wbase = blockIdx.x * 64;      // wave's first element

    __shared__ float4 lin[2][576];          // input double buffer, 18432 B
    __shared__ float4 lout[832];            // 64 elems x (12+1 pad), 13312 B

    const float4* __restrict__ gbase =
        reinterpret_cast<const float4*>(angles) + (size_t)wbase * 72u;
    float4* __restrict__ gout =
        reinterpret_cast<float4*>(out) + (size_t)wbase * 24u;

    // Diagonal gather: DMA instr t, lane L fetches tile float4 #n (n=64t+L)
    // at global float4 (n/9)*72 + (n%9); lands at LDS slot n (elem-major).
    const float4* gp[9];
#pragma unroll
    for (int t = 0; t < 9; ++t) {
        const int n = t * 64 + lane;
        const int e = n / 9;
        const int q = n - e * 9;
        gp[t] = gbase + (e * 72 + q);
    }

    // Prologue: group 0 -> buffer 0.
#pragma unroll
    for (int t = 0; t < 9; ++t)
        __builtin_amdgcn_global_load_lds(
            (const __attribute__((address_space(1))) void*)(gp[t]),
            (__attribute__((address_space(3))) void*)(&lin[0][t * 64]),
            16, 0, 0);

    float rot[32][3][3];
    float pos[32][3];

#pragma unroll
    for (int g = 0; g < 8; ++g) {
        if (g < 7) {
            // Ensure pending ds_reads from the buffer we're about to
            // overwrite (and flush-0's lout ds_reads) have landed in VGPRs.
            ASM_LGKM0();
#pragma unroll
            for (int t = 0; t < 9; ++t)
                __builtin_amdgcn_global_load_lds(
                    (const __attribute__((address_space(1))) void*)(gp[t] + 9 * (g + 1)),
                    (__attribute__((address_space(3))) void*)(&lin[(g + 1) & 1][t * 64]),
                    16, 0, 0);
        }
        // Wait for THIS group's 9 DMAs only (FIFO vmcnt retirement).
        // g==4: FIFO is [g4 x9 | flush0 stores x12 | g5 x9] -> all but the
        //       youngest 21 retired guarantees g4's DMAs are done.
        if (g == 7)      { ASM_VMCNT(0);  }
        else if (g == 4) { ASM_VMCNT(21); }
        else             { ASM_VMCNT(9);  }

        // Own element's 36 floats: 9 x ds_read_b128 (2-way bank alias: free).
        float a[36];
#pragma unroll
        for (int q = 0; q < 9; ++q) {
            const float4 v = lin[g & 1][lane * 9 + q];
            a[4*q+0] = v.x; a[4*q+1] = v.y; a[4*q+2] = v.z; a[4*q+3] = v.w;
        }

#pragma unroll
        for (int jj = 0; jj < 4; ++jj) {
            const int j = g * 4 + jj;
            if (j == 0) {
#pragma unroll
                for (int i = 0; i < 3; ++i)
#pragma unroll
                    for (int l = 0; l < 3; ++l)
                        rot[0][i][l] = a[i*3 + l];
                pos[0][0] = 0.f; pos[0][1] = 0.f; pos[0][2] = 0.f;
            } else {
                const int p = PAR[j];
                const float o0 = offsets[j*3+0];   // uniform -> s_load
                const float o1 = offsets[j*3+1];
                const float o2 = offsets[j*3+2];
#pragma unroll
                for (int l = 0; l < 3; ++l)
                    pos[j][l] = fmaf(o0, rot[p][0][l],
                               fmaf(o1, rot[p][1][l],
                               fmaf(o2, rot[p][2][l], pos[p][l])));
                // rot[j] dead for leaf joints -> DCE.
#pragma unroll
                for (int i = 0; i < 3; ++i) {
                    const float a0 = a[jj*9 + i*3 + 0];
                    const float a1 = a[jj*9 + i*3 + 1];
                    const float a2 = a[jj*9 + i*3 + 2];
#pragma unroll
                    for (int l = 0; l < 3; ++l)
                        rot[j][i][l] = fmaf(a0, rot[p][0][l],
                                      fmaf(a1, rot[p][1][l],
                                           a2 * rot[p][2][l]));
                }
            }
        }

        // Stash this group's 4 joint positions (12 floats = 3 float4) into
        // padded LDS; stride 13 f4 -> banks (52L)%32 = perfect 8-lane spread.
        {
            const int gg = g & 3;
            const int j0 = g * 4;
            lout[lane*13 + gg*3 + 0] = make_float4(pos[j0+0][0], pos[j0+0][1], pos[j0+0][2], pos[j0+1][0]);
            lout[lane*13 + gg*3 + 1] = make_float4(pos[j0+1][1], pos[j0+1][2], pos[j0+2][0], pos[j0+2][1]);
            lout[lane*13 + gg*3 + 2] = make_float4(pos[j0+2][2], pos[j0+3][0], pos[j0+3][1], pos[j0+3][2]);
        }

        // Flush pass 0 (joints 0-15) after group 3; pass 1 after group 7.
        if (g == 3 || g == 7) {
            const int h = (g == 3) ? 0 : 1;
#pragma unroll
            for (int s = 0; s < 12; ++s) {
                const int n = s * 64 + lane;     // wave-tile float4 index
                const int e = n / 12;
                const int q = n - e * 12;
                const float4 v = lout[e*13 + q];
                gout[e*24 + h*12 + q] = v;       // 192B-aligned full lines
            }
        }
    }
}

extern "C" void kernel_launch(void* const* d_in, const int* in_sizes, int n_in,
                              void* d_out, int out_size, void* d_ws, size_t ws_size,
                              hipStream_t stream) {
    const float* angles  = (const float*)d_in[0];
    const float* offsets = (const float*)d_in[1];
    float* out = (float*)d_out;
    const int B = in_sizes[0] / 288;   // [B, 32, 3, 3], B % 64 == 0
    const int block = 64;
    const int grid = B / block;
    fk32_kernel<<<grid, block, 0, stream>>>(angles, offsets, out, B);
}